// Round 7
// baseline (230.333 us; speedup 1.0000x reference)
//
#include <hip/hip_runtime.h>

#define D 128
#define BM 64

typedef __attribute__((ext_vector_type(8))) short bf16x8;
typedef __attribute__((ext_vector_type(4))) float f32x4;

// ---- bf16 helpers (RNE) ---------------------------------------------------
__device__ __forceinline__ float bf2f(unsigned short u) {
    union { unsigned int i; float f; } v; v.i = ((unsigned int)u) << 16; return v.f;
}
__device__ __forceinline__ unsigned short f2bf(float f) {
    union { float f; unsigned int i; } v; v.f = f;
    unsigned int x = v.i;
    unsigned int r = (x + 0x7fffu + ((x >> 16) & 1u)) >> 16;   // RNE
    return (unsigned short)r;
}

// ---------------------------------------------------------------------------
// Kernel 1: prep — dtype detect, histogram+rank (packed (rank<<18)|tgt),
// compact nbr32, x -> bf16, pack weights into MFMA-B-fragment order.
// B layout: chunk q in [0,4096): g=q&3, c=(q>>2)&127, s=q>>9;
//   Bp[q*8+j] = W[k=s*32+g*8+j][c]  (W = Wl for k<128 else Wr)
// ---------------------------------------------------------------------------
__global__ __launch_bounds__(256) void gs_prep(
    const float* __restrict__ x, const float* __restrict__ Wl,
    const float* __restrict__ Wr, const int* __restrict__ ei,
    unsigned short* __restrict__ x_bf, unsigned short* __restrict__ Bp,
    unsigned int* __restrict__ packed, int* __restrict__ nbr32,
    int* __restrict__ counts, int n, int E) {
    __shared__ int sflag;
    // dtype detect on the SAME window (first 64 edges) in every block:
    // int64 little-endian with values < 2^31 => all odd words zero.
    if (threadIdx.x < 64) {
        int lim = (E < 64) ? E : 64;
        int odd = (threadIdx.x < lim) ? ei[2 * threadIdx.x + 1] : 0;
        unsigned long long b = __ballot(odd != 0);
        if (threadIdx.x == 0) sflag = (b != 0ULL) ? 1 : 0;
    }
    __syncthreads();
    const int is32 = sflag;
    const int tid0 = blockIdx.x * 256 + threadIdx.x;
    const int stride = gridDim.x * 256;

    // decode + histogram + rank + compact nbr
    for (int e = tid0; e < E; e += stride) {
        int tgt, nbr;
        if (is32) { tgt = ei[e];     nbr = ei[E + e]; }
        else      { tgt = ei[2 * e]; nbr = ei[2 * (E + e)]; }
        nbr32[e] = nbr;
        if ((unsigned)tgt < (unsigned)n && (unsigned)nbr < (unsigned)n) {
            unsigned int rank = (unsigned int)atomicAdd(&counts[tgt], 1);
            packed[e] = (rank << 18) | (unsigned int)tgt;
        } else {
            packed[e] = 0xFFFFFFFFu;   // tgt-field decodes >= n -> skipped
        }
    }
    // x -> bf16 (8 elems / iter)
    const int nch = n * (D / 8);
    for (int i = tid0; i < nch; i += stride) {
        const float4 a = *(const float4*)(x + (size_t)i * 8);
        const float4 b = *(const float4*)(x + (size_t)i * 8 + 4);
        unsigned short o[8] = {f2bf(a.x), f2bf(a.y), f2bf(a.z), f2bf(a.w),
                               f2bf(b.x), f2bf(b.y), f2bf(b.z), f2bf(b.w)};
        *(uint4*)(x_bf + (size_t)i * 8) = *(const uint4*)o;
    }
    // weight pack (4096 chunks)
    for (int q = tid0; q < 4096; q += stride) {
        int g = q & 3, c = (q >> 2) & 127, s = q >> 9;
        unsigned short o[8];
#pragma unroll
        for (int j = 0; j < 8; ++j) {
            int k = s * 32 + g * 8 + j;
            float w = (k < 128) ? Wl[k * 128 + c] : Wr[(k - 128) * 128 + c];
            o[j] = f2bf(w);
        }
        *(uint4*)(Bp + (size_t)q * 8) = *(const uint4*)o;
    }
}

// ---------------------------------------------------------------------------
// Kernel 2a/2b: two-level exclusive scan of counts.
// ---------------------------------------------------------------------------
__global__ __launch_bounds__(256) void gs_scanA(const int* __restrict__ counts,
                                                int* __restrict__ offs,
                                                int* __restrict__ partials, int n) {
    __shared__ int s[256];
    const int tid = threadIdx.x;
    const int i = blockIdx.x * 256 + tid;
    int v = (i < n) ? counts[i] : 0;
    s[tid] = v;
    __syncthreads();
    for (int off = 1; off < 256; off <<= 1) {
        int t = (tid >= off) ? s[tid - off] : 0;
        __syncthreads();
        s[tid] += t;
        __syncthreads();
    }
    if (i < n) offs[i] = s[tid] - v;
    if (tid == 255) partials[blockIdx.x] = s[255];
}

__global__ __launch_bounds__(512) void gs_scanB(int* __restrict__ partials, int nb) {
    __shared__ int s[512];
    const int tid = threadIdx.x;
    int v = (tid < nb) ? partials[tid] : 0;
    s[tid] = v;
    __syncthreads();
    for (int off = 1; off < 512; off <<= 1) {
        int t = (tid >= off) ? s[tid - off] : 0;
        __syncthreads();
        s[tid] += t;
        __syncthreads();
    }
    if (tid < nb) partials[tid] = s[tid] - v;
}

// ---------------------------------------------------------------------------
// Kernel 3: bin neighbors into CSR slots — no atomics, compact inputs.
// ---------------------------------------------------------------------------
__global__ void gs_bin(const unsigned int* __restrict__ packed,
                       const int* __restrict__ nbr32,
                       const int* __restrict__ offs, const int* __restrict__ partials,
                       int* __restrict__ sorted_nbr, int E, int n) {
    int e = blockIdx.x * blockDim.x + threadIdx.x;
    if (e >= E) return;
    unsigned int v = packed[e];
    unsigned int tgt = v & 0x3FFFFu;
    if (tgt >= (unsigned)n) return;
    int p = offs[tgt] + partials[tgt >> 8] + (int)(v >> 18);
    sorted_nbr[p] = nbr32[e];
}

// ---------------------------------------------------------------------------
// Kernel 4: segmented mean over bf16 x. One wave per node; quarter-wave per
// neighbor row. Indices preloaded into lanes 0..15 (one coalesced shot) and
// distributed via shfl, so up to 4 row-gathers issue back-to-back with no
// dependent index loads. Fallback loop for cnt>16 (<0.5% of nodes).
// ---------------------------------------------------------------------------
__global__ __launch_bounds__(256) void gs_agg(
    const int* __restrict__ sorted_nbr, const int* __restrict__ counts,
    const int* __restrict__ offs, const int* __restrict__ partials,
    const unsigned short* __restrict__ x_bf, unsigned short* __restrict__ agg_bf,
    int n) {
    int node = blockIdx.x * 4 + (threadIdx.x >> 6);
    if (node >= n) return;
    const int lane = threadIdx.x & 63;
    const int qw = lane >> 4, c = lane & 15;
    const int cnt = counts[node];
    const int start = offs[node] + partials[node >> 8];

    // preload up to 16 indices (lanes l&15 load idx[l&15]; 4 redundant copies)
    int idxreg = 0;
    {
        int j = lane & 15;
        if (j < cnt) idxreg = sorted_nbr[start + j];
    }

    float a[8] = {};
    // batched gathers: rows qw, qw+4, qw+8, qw+12 issued independently
    uint4 r[4];
    int have[4] = {0, 0, 0, 0};
#pragma unroll
    for (int t = 0; t < 4; ++t) {
        int j = qw + 4 * t;
        if (j < cnt && j < 16) {
            int nb = __shfl(idxreg, j, 64);
            r[t] = *(const uint4*)(x_bf + (size_t)nb * D + c * 8);
            have[t] = 1;
        }
    }
#pragma unroll
    for (int t = 0; t < 4; ++t) {
        if (have[t]) {
            const unsigned short* u = (const unsigned short*)&r[t];
#pragma unroll
            for (int e = 0; e < 8; ++e) a[e] += bf2f(u[e]);
        }
    }
    // rare tail: cnt > 16
    for (int j = 16 + qw; j < cnt; j += 4) {
        int nb = sorted_nbr[start + j];
        uint4 rr = *(const uint4*)(x_bf + (size_t)nb * D + c * 8);
        const unsigned short* u = (const unsigned short*)&rr;
#pragma unroll
        for (int e = 0; e < 8; ++e) a[e] += bf2f(u[e]);
    }

#pragma unroll
    for (int e = 0; e < 8; ++e) {
        a[e] += __shfl_xor(a[e], 16, 64);
        a[e] += __shfl_xor(a[e], 32, 64);
    }
    if (qw == 0) {
        const float inv = (cnt > 0) ? (1.0f / (float)cnt) : 0.0f;
        unsigned short o[8];
#pragma unroll
        for (int e = 0; e < 8; ++e) o[e] = f2bf(a[e] * inv);
        *(uint4*)(agg_bf + (size_t)node * D + c * 8) = *(const uint4*)o;
    }
}

// ---------------------------------------------------------------------------
// Kernel 5: fused MFMA GEMM  out = normalize(relu([x|agg] @ [Wl;Wr] + bl+br))
// M-tile 64 rows, 4 waves; wave w owns rows w*16..w*16+15, all 128 cols.
// A staged in LDS (XOR-swizzled 16B chunks); B frags pre-packed (L2-hot).
// Frag maps (m89-verified): A row=l&15,k=(l>>4)*8+j; B k=(l>>4)*8+j,col=l&15;
// C/D col=l&15, row=(l>>4)*4+r.
// ---------------------------------------------------------------------------
__global__ __launch_bounds__(256) void gs_fused(
    const unsigned short* __restrict__ x_bf, const unsigned short* __restrict__ agg_bf,
    const unsigned short* __restrict__ Bp,
    const float* __restrict__ bl, const float* __restrict__ br,
    float* __restrict__ out, int n) {
    __shared__ unsigned short sA[BM][256];   // 32 KB

    const int tid = threadIdx.x;
    const int wave = tid >> 6, lane = tid & 63;
    const int g = lane >> 4, c = lane & 15;
    const int r0 = blockIdx.x * BM;

    // stage A: 64 rows x 32 chunks(16B). chunk<16 from x_bf, else agg_bf.
#pragma unroll
    for (int it = 0; it < 8; ++it) {
        int idx = it * 256 + tid;
        int row = idx >> 5, ch = idx & 31;
        int grow = r0 + row;
        uint4 val = make_uint4(0u, 0u, 0u, 0u);
        if (grow < n) {
            const unsigned short* src = (ch < 16)
                ? (x_bf + (size_t)grow * D + ch * 8)
                : (agg_bf + (size_t)grow * D + (ch - 16) * 8);
            val = *(const uint4*)src;
        }
        int sch = ch ^ (row & 7);
        *(uint4*)((char*)&sA[0][0] + row * 512 + sch * 16) = val;
    }
    __syncthreads();

    f32x4 acc[8] = {};
    const int arow = wave * 16 + c;
    const int axor = (arow & 7);
#pragma unroll
    for (int s = 0; s < 8; ++s) {
        bf16x8 afrag = *(const bf16x8*)((const char*)&sA[0][0] +
                                        arow * 512 + (((s * 4 + g) ^ axor) * 16));
#pragma unroll
        for (int f = 0; f < 8; ++f) {
            bf16x8 bfrag = *(const bf16x8*)(Bp + (size_t)(((s * 128 + f * 16 + c) * 4 + g) * 8));
            acc[f] = __builtin_amdgcn_mfma_f32_16x16x32_bf16(afrag, bfrag, acc[f], 0, 0, 0);
        }
    }

    // epilogue: bias + relu, row sumsq (16-lane shfl_xor), normalize, store
    float v[8][4];
    float sumsq[4] = {0.f, 0.f, 0.f, 0.f};
#pragma unroll
    for (int f = 0; f < 8; ++f) {
        float bb = bl[f * 16 + c] + br[f * 16 + c];
#pragma unroll
        for (int r = 0; r < 4; ++r) {
            float y = fmaxf(acc[f][r] + bb, 0.f);
            v[f][r] = y;
            sumsq[r] += y * y;
        }
    }
#pragma unroll
    for (int r = 0; r < 4; ++r) {
        float s = sumsq[r];
        s += __shfl_xor(s, 1, 64);
        s += __shfl_xor(s, 2, 64);
        s += __shfl_xor(s, 4, 64);
        s += __shfl_xor(s, 8, 64);
        sumsq[r] = 1.0f / (sqrtf(s) + 1e-6f);
    }
    const int baserow = r0 + wave * 16 + g * 4;
#pragma unroll
    for (int r = 0; r < 4; ++r) {
        int row = baserow + r;
        if (row < n) {
#pragma unroll
            for (int f = 0; f < 8; ++f)
                out[(size_t)row * D + f * 16 + c] = v[f][r] * sumsq[r];
        }
    }
}

// ---------------------------------------------------------------------------
extern "C" void kernel_launch(void* const* d_in, const int* in_sizes, int n_in,
                              void* d_out, int out_size, void* d_ws, size_t ws_size,
                              hipStream_t stream) {
    const float* x  = (const float*)d_in[0];
    const int*   ei = (const int*)d_in[1];
    const float* Wl = (const float*)d_in[2];
    const float* bl = (const float*)d_in[3];
    const float* Wr = (const float*)d_in[4];
    const float* br = (const float*)d_in[5];
    float* out = (float*)d_out;

    const int n = in_sizes[0] / D;
    const int E = in_sizes[1] / 2;
    const int nb = (n + 255) / 256;          // 391 for n=100000 (<=512)

    // workspace layout (~62 MB)
    unsigned short* x_bf   = (unsigned short*)d_ws;                 // n*128
    unsigned short* agg_bf = x_bf + (size_t)n * D;                  // n*128
    unsigned short* Bp     = agg_bf + (size_t)n * D;                // 32768
    int* counts   = (int*)(Bp + 32768);                             // n
    int* offs     = counts + n;                                     // n
    int* partials = offs + n;                                       // 512
    unsigned int* packed = (unsigned int*)(partials + 512);         // E
    int* nbr32    = (int*)(packed + E);                             // E
    int* sorted   = nbr32 + E;                                      // E

    hipMemsetAsync(counts, 0, (size_t)n * sizeof(int), stream);
    gs_prep<<<4096, 256, 0, stream>>>(x, Wl, Wr, ei, x_bf, Bp, packed, nbr32, counts, n, E);
    gs_scanA<<<nb, 256, 0, stream>>>(counts, offs, partials, n);
    gs_scanB<<<1, 512, 0, stream>>>(partials, nb);
    gs_bin<<<(E + 255) / 256, 256, 0, stream>>>(packed, nbr32, offs, partials, sorted, E, n);
    gs_agg<<<(n + 3) / 4, 256, 0, stream>>>(sorted, counts, offs, partials, x_bf, agg_bf, n);
    gs_fused<<<(n + BM - 1) / BM, 256, 0, stream>>>(x_bf, agg_bf, Bp, bl, br, out, n);
}